// Round 9
// baseline (206.415 us; speedup 1.0000x reference)
//
#include <hip/hip_runtime.h>

#define N1 1000000
#define N2 131072
#define N3 16384
#define N4 2048
#define N5 256
#define C 48
#define CAP 48   // max rows per segment; P(Binomial(1M,1/131072) >= 48) ~ 1e-17

// ---------------------------------------------------------------- zero ws
__global__ void zero_kernel(float4* __restrict__ p, int n4) {
    int i = blockIdx.x * blockDim.x + threadIdx.x;
    if (i < n4) p[i] = make_float4(0.f, 0.f, 0.f, 0.f);
}

// --------- direct-slot counting sort: no histogram/scan kernels needed
__global__ void reorder_direct_kernel(const int* __restrict__ parent,
                                      int* __restrict__ cnt,
                                      int* __restrict__ rowid, int n) {
    int i = blockIdx.x * blockDim.x + threadIdx.x;
    if (i >= n) return;
    int p = parent[i];
    int s = atomicAdd(&cnt[p], 1);
    if (s < CAP) rowid[p * CAP + s] = i;
}

// --------------------- fused: segment-sum + row-argmax + f3 accumulation
// One 64-lane wave per segment. Lane l = (group g=l/12, quad c4=l%12):
// loads float4 of channels [4*c4,4*c4+3] of row (k+g) -> each load
// instruction fetches FIVE random rows (5x memory parallelism/instr).
// Cross-group reduce via 16 shuffles; epilogue on lanes 0..11 in float4.
__global__ void segsum_fused_kernel(const float* __restrict__ src,
                                    const int* __restrict__ rowid,
                                    const int* __restrict__ cnt,
                                    const int* __restrict__ parent3,
                                    float* __restrict__ f3,
                                    unsigned char* __restrict__ tab2, int nseg) {
    int wid = threadIdx.x >> 6;
    int lane = threadIdx.x & 63;
    int seg = blockIdx.x * 4 + wid;
    if (seg >= nseg) return;
    int n = cnt[seg];
    if (n > CAP) n = CAP;                       // safety clamp (never hit)
    int rv = (lane < n) ? rowid[seg * CAP + lane] : 0;
    int g = lane / 12;                          // 0..4 active, 5 = idle lanes 60-63
    int c4 = lane - g * 12;                     // 0..11
    const bool act = (lane < 60);
    float4 acc = make_float4(0.f, 0.f, 0.f, 0.f);
    for (int k = 0; k < n; k += 10) {           // two 5-row bursts in flight
        int r0 = __shfl(rv, k + g);
        int r1 = __shfl(rv, k + 5 + g);
        bool p0 = act && (k + g < n);
        bool p1 = act && (k + 5 + g < n);
        float4 v0 = p0 ? *(const float4*)(src + (size_t)r0 * C + c4 * 4)
                       : make_float4(0.f, 0.f, 0.f, 0.f);
        float4 v1 = p1 ? *(const float4*)(src + (size_t)r1 * C + c4 * 4)
                       : make_float4(0.f, 0.f, 0.f, 0.f);
        acc.x += v0.x + v1.x;
        acc.y += v0.y + v1.y;
        acc.z += v0.z + v1.z;
        acc.w += v0.w + v1.w;
    }
    // ---- reduce across the 5 row-groups (valid on lanes 0..11)
    float4 tot = acc;
#pragma unroll
    for (int gg = 1; gg < 5; ++gg) {
        int sl = c4 + 12 * gg;
        tot.x += __shfl(acc.x, sl);
        tot.y += __shfl(acc.y, sl);
        tot.z += __shfl(acc.z, sl);
        tot.w += __shfl(acc.w, sl);
    }
    // ---- accumulate this f2 row into f3 (lanes 0..11, 4 channels each)
    int p3 = parent3[seg];
    if (lane < 12) {
        float* dst = &f3[(size_t)p3 * C + lane * 4];
        atomicAdd(dst + 0, tot.x);
        atomicAdd(dst + 1, tot.y);
        atomicAdd(dst + 2, tot.z);
        atomicAdd(dst + 3, tot.w);
    }
    // ---- argmax of the f2 row (first-max tie-break: smaller index)
    float bv = -__builtin_inff();
    int bi = 0x7fffffff;
    if (lane < 12) {
        bv = tot.x; bi = lane * 4;
        if (tot.y > bv) { bv = tot.y; bi = lane * 4 + 1; }
        if (tot.z > bv) { bv = tot.z; bi = lane * 4 + 2; }
        if (tot.w > bv) { bv = tot.w; bi = lane * 4 + 3; }
    }
#pragma unroll
    for (int d = 1; d < 16; d <<= 1) {          // lanes 0..15 (12..15 = -inf)
        float ov = __shfl_xor(bv, d);
        int oi = __shfl_xor(bi, d);
        if (ov > bv || (ov == bv && oi < bi)) { bv = ov; bi = oi; }
    }
    if (lane == 0) tab2[seg] = (unsigned char)bi;
}

// ------------------------------------------------------- per-row argmax
__device__ __forceinline__ int argmax48(const float4* __restrict__ row) {
    float best = -__builtin_inff();
    int bi = 0;
#pragma unroll
    for (int i = 0; i < 12; ++i) {
        float4 v = row[i];
        if (v.x > best) { best = v.x; bi = 4 * i + 0; }
        if (v.y > best) { best = v.y; bi = 4 * i + 1; }
        if (v.z > best) { best = v.z; bi = 4 * i + 2; }
        if (v.w > best) { best = v.w; bi = 4 * i + 3; }
    }
    return bi;
}

// ----------- fused level kernel: atomic scatter (blocks < nblkA) + row argmax
__global__ void level_kernel(const float* __restrict__ fsrc,
                             const int* __restrict__ parent,
                             float* __restrict__ fdst,
                             unsigned char* __restrict__ tabsrc,
                             int nrows, int nblkA) {
    if ((int)blockIdx.x < nblkA) {
        int e = blockIdx.x * 256 + threadIdx.x;
        if (e < nrows * C) {
            unsigned r = (unsigned)e / C;
            unsigned c = (unsigned)e - r * C;
            atomicAdd(&fdst[(unsigned)parent[r] * C + c], fsrc[e]);
        }
    } else {
        int r = (blockIdx.x - nblkA) * 256 + threadIdx.x;
        if (r < nrows) tabsrc[r] = (unsigned char)argmax48((const float4*)fsrc + r * 12);
    }
}

// --------------- final gather: tab2/3/4 lookups + LDS-cached tab5
__global__ void final_kernel(const unsigned char* __restrict__ tab2,
                             const unsigned char* __restrict__ tab3,
                             const unsigned char* __restrict__ tab4,
                             const float4* __restrict__ f5,
                             const int4* __restrict__ idx2,
                             const int4* __restrict__ idx3,
                             const int4* __restrict__ idx4,
                             const int4* __restrict__ idx5,
                             int4* __restrict__ out) {
    __shared__ unsigned char t5[N5];
    int tid = threadIdx.x;
    t5[tid] = (unsigned char)argmax48(f5 + tid * 12);   // 256 threads = 256 rows
    __syncthreads();
    const int NQ = N1 / 4;
    int t = blockIdx.x * blockDim.x + tid;
    if (t >= NQ) return;
    int4 a = idx2[t], b = idx3[t], c = idx4[t], d = idx5[t];
    out[t] = make_int4(tab2[a.x], tab2[a.y], tab2[a.z], tab2[a.w]);
    out[NQ + t] = make_int4(tab3[b.x], tab3[b.y], tab3[b.z], tab3[b.w]);
    out[2 * NQ + t] = make_int4(tab4[c.x], tab4[c.y], tab4[c.z], tab4[c.w]);
    out[3 * NQ + t] = make_int4(t5[d.x], t5[d.y], t5[d.z], t5[d.w]);
}

extern "C" void kernel_launch(void* const* d_in, const int* in_sizes, int n_in,
                              void* d_out, int out_size, void* d_ws, size_t ws_size,
                              hipStream_t stream) {
    const float* slabel  = (const float*)d_in[0];
    const int* parent2   = (const int*)d_in[1];
    const int* parent3   = (const int*)d_in[2];
    const int* parent4   = (const int*)d_in[3];
    const int* parent5   = (const int*)d_in[4];
    const int* idx2      = (const int*)d_in[5];
    const int* idx3      = (const int*)d_in[6];
    const int* idx4      = (const int*)d_in[7];
    const int* idx5      = (const int*)d_in[8];
    int* out = (int*)d_out;   // JAX argmax output dtype is int32

    // ---- workspace layout (dwords) ----
    // zeroed: [f3 | f4 | f5 | cnt2]
    // unzeroed: [rowid2 (N2*CAP) | tab2 | tab3 | tab4 (bytes)]
    float* f3 = (float*)d_ws;
    float* f4 = f3 + (size_t)N3 * C;
    float* f5 = f4 + (size_t)N4 * C;
    int* cnt2 = (int*)(f5 + (size_t)N5 * C);
    int* rowid2 = cnt2 + N2;                 // end of zeroed region
    unsigned char* tab2 = (unsigned char*)(rowid2 + (size_t)N2 * CAP);
    unsigned char* tab3 = tab2 + N2;
    unsigned char* tab4 = tab3 + N3;

    // zero: f3 + f4 + f5 + cnt2 = 1,028,096 dwords = 257,024 float4
    const int zero_f4 = ((N3 + N4 + N5) * C + N2) / 4;

    // 1) zero accumulators + counters (ws poisoned between calls)
    zero_kernel<<<(zero_f4 + 255) / 256, 256, 0, stream>>>((float4*)d_ws, zero_f4);

    // 2) direct-slot counting sort
    reorder_direct_kernel<<<(N1 + 255) / 256, 256, 0, stream>>>(
        parent2, cnt2, rowid2, N1);

    // 3) fused: 5-rows-per-load segment-sum + argmax->tab2 + atomic f3
    segsum_fused_kernel<<<N2 / 4, 256, 0, stream>>>(
        slabel, rowid2, cnt2, parent3, f3, tab2, N2);

    // 4) level 3: f3->f4 atomics (3072 blocks) + tab3 argmax (64 blocks)
    level_kernel<<<3072 + 64, 256, 0, stream>>>(f3, parent4, f4, tab3, N3, 3072);

    // 5) level 4: f4->f5 atomics (384 blocks) + tab4 argmax (8 blocks)
    level_kernel<<<384 + 8, 256, 0, stream>>>(f4, parent5, f5, tab4, N4, 384);

    // 6) final: tab lookups + per-block LDS tab5
    final_kernel<<<(N1 / 4 + 255) / 256, 256, 0, stream>>>(
        tab2, tab3, tab4, (const float4*)f5,
        (const int4*)idx2, (const int4*)idx3, (const int4*)idx4, (const int4*)idx5,
        (int4*)out);
}

// Round 11
// 169.672 us; speedup vs baseline: 1.2166x; 1.2166x over previous
//
#include <hip/hip_runtime.h>

#define N1 1000000
#define N2 131072
#define N3 16384
#define N4 2048
#define N5 256
#define C 48
#define CAP 48   // max rows per segment; P(Binomial(1M,1/131072) >= 48) ~ 1e-17

// ---------------------------------------------------------------- zero ws
__global__ void zero_kernel(float4* __restrict__ p, int n4) {
    int i = blockIdx.x * blockDim.x + threadIdx.x;
    if (i < n4) p[i] = make_float4(0.f, 0.f, 0.f, 0.f);
}

// --------- direct-slot counting sort: no histogram/scan kernels needed
__global__ void reorder_direct_kernel(const int* __restrict__ parent,
                                      int* __restrict__ cnt,
                                      int* __restrict__ rowid, int n) {
    int i = blockIdx.x * blockDim.x + threadIdx.x;
    if (i >= n) return;
    int p = parent[i];
    int s = atomicAdd(&cnt[p], 1);
    if (s < CAP) rowid[p * CAP + s] = i;
}

// --------------------- fused: segment-sum + row-argmax + f3 accumulation
// One 64-lane wave per segment. Load phase: lane l = (group g=l/12, quad
// c4=l%12) loads float4 of channels [4*c4,4*c4+3] of row (k+g) -> each
// load instruction fetches FIVE random rows; 3 bursts = 15 rows/iter.
// Epilogue: reduce 5 groups (16 shfl), redistribute to 48 contiguous
// lanes (4 shfl) -> ONE contiguous 48-lane atomicAdd (round-8 write
// pattern, 4x less write-through than strided quads) + argmax butterfly.
__global__ void segsum_fused_kernel(const float* __restrict__ src,
                                    const int* __restrict__ rowid,
                                    const int* __restrict__ cnt,
                                    const int* __restrict__ parent3,
                                    float* __restrict__ f3,
                                    unsigned char* __restrict__ tab2, int nseg) {
    int wid = threadIdx.x >> 6;
    int lane = threadIdx.x & 63;
    int seg = blockIdx.x * 4 + wid;
    if (seg >= nseg) return;
    int n = cnt[seg];
    if (n > CAP) n = CAP;                       // safety clamp (never hit)
    int rv = (lane < n) ? rowid[seg * CAP + lane] : 0;
    int g = lane / 12;                          // 0..4 active, 5 = lanes 60-63
    int c4 = lane - g * 12;                     // 0..11
    const bool act = (lane < 60);
    float4 acc = make_float4(0.f, 0.f, 0.f, 0.f);
    for (int k = 0; k < n; k += 15) {           // three 5-row bursts in flight
        int r0 = __shfl(rv, k + g);
        int r1 = __shfl(rv, k + 5 + g);
        int r2 = __shfl(rv, k + 10 + g);
        bool p0 = act && (k + g < n);
        bool p1 = act && (k + 5 + g < n);
        bool p2 = act && (k + 10 + g < n);
        float4 v0 = p0 ? *(const float4*)(src + (size_t)r0 * C + c4 * 4)
                       : make_float4(0.f, 0.f, 0.f, 0.f);
        float4 v1 = p1 ? *(const float4*)(src + (size_t)r1 * C + c4 * 4)
                       : make_float4(0.f, 0.f, 0.f, 0.f);
        float4 v2 = p2 ? *(const float4*)(src + (size_t)r2 * C + c4 * 4)
                       : make_float4(0.f, 0.f, 0.f, 0.f);
        acc.x += v0.x + v1.x + v2.x;
        acc.y += v0.y + v1.y + v2.y;
        acc.z += v0.z + v1.z + v2.z;
        acc.w += v0.w + v1.w + v2.w;
    }
    // ---- reduce across the 5 row-groups (valid on lanes 0..11)
    float4 tot = acc;
#pragma unroll
    for (int gg = 1; gg < 5; ++gg) {
        int sl = c4 + 12 * gg;
        tot.x += __shfl(acc.x, sl);
        tot.y += __shfl(acc.y, sl);
        tot.z += __shfl(acc.z, sl);
        tot.w += __shfl(acc.w, sl);
    }
    // ---- redistribute: lane l (0..47) takes channel l = comp l%4 of quad l/4
    int q = lane >> 2;
    float vx = __shfl(tot.x, q);
    float vy = __shfl(tot.y, q);
    float vz = __shfl(tot.z, q);
    float vw = __shfl(tot.w, q);
    int m = lane & 3;
    float val = (m == 0) ? vx : (m == 1) ? vy : (m == 2) ? vz : vw;
    // ---- ONE contiguous 48-lane atomic into f3 (round-8 write pattern)
    int p3 = parent3[seg];
    const bool ch = (lane < C);
    if (ch) atomicAdd(&f3[(size_t)p3 * C + lane], val);
    // ---- wave argmax of the f2 row (first-max tie-break: smaller index)
    float bv = ch ? val : -__builtin_inff();
    int bi = ch ? lane : 0x7fffffff;
#pragma unroll
    for (int d = 32; d > 0; d >>= 1) {
        float ov = __shfl_xor(bv, d);
        int oi = __shfl_xor(bi, d);
        if (ov > bv || (ov == bv && oi < bi)) { bv = ov; bi = oi; }
    }
    if (lane == 0) tab2[seg] = (unsigned char)bi;
}

// ------------------------------------------------------- per-row argmax
__device__ __forceinline__ int argmax48(const float4* __restrict__ row) {
    float best = -__builtin_inff();
    int bi = 0;
#pragma unroll
    for (int i = 0; i < 12; ++i) {
        float4 v = row[i];
        if (v.x > best) { best = v.x; bi = 4 * i + 0; }
        if (v.y > best) { best = v.y; bi = 4 * i + 1; }
        if (v.z > best) { best = v.z; bi = 4 * i + 2; }
        if (v.w > best) { best = v.w; bi = 4 * i + 3; }
    }
    return bi;
}

// ----------- fused level kernel: atomic scatter (blocks < nblkA) + row argmax
__global__ void level_kernel(const float* __restrict__ fsrc,
                             const int* __restrict__ parent,
                             float* __restrict__ fdst,
                             unsigned char* __restrict__ tabsrc,
                             int nrows, int nblkA) {
    if ((int)blockIdx.x < nblkA) {
        int e = blockIdx.x * 256 + threadIdx.x;
        if (e < nrows * C) {
            unsigned r = (unsigned)e / C;
            unsigned c = (unsigned)e - r * C;
            atomicAdd(&fdst[(unsigned)parent[r] * C + c], fsrc[e]);
        }
    } else {
        int r = (blockIdx.x - nblkA) * 256 + threadIdx.x;
        if (r < nrows) tabsrc[r] = (unsigned char)argmax48((const float4*)fsrc + r * 12);
    }
}

// --------------- final gather: tab2/3/4 lookups + LDS-cached tab5
__global__ void final_kernel(const unsigned char* __restrict__ tab2,
                             const unsigned char* __restrict__ tab3,
                             const unsigned char* __restrict__ tab4,
                             const float4* __restrict__ f5,
                             const int4* __restrict__ idx2,
                             const int4* __restrict__ idx3,
                             const int4* __restrict__ idx4,
                             const int4* __restrict__ idx5,
                             int4* __restrict__ out) {
    __shared__ unsigned char t5[N5];
    int tid = threadIdx.x;
    t5[tid] = (unsigned char)argmax48(f5 + tid * 12);   // 256 threads = 256 rows
    __syncthreads();
    const int NQ = N1 / 4;
    int t = blockIdx.x * blockDim.x + tid;
    if (t >= NQ) return;
    int4 a = idx2[t], b = idx3[t], c = idx4[t], d = idx5[t];
    out[t] = make_int4(tab2[a.x], tab2[a.y], tab2[a.z], tab2[a.w]);
    out[NQ + t] = make_int4(tab3[b.x], tab3[b.y], tab3[b.z], tab3[b.w]);
    out[2 * NQ + t] = make_int4(tab4[c.x], tab4[c.y], tab4[c.z], tab4[c.w]);
    out[3 * NQ + t] = make_int4(t5[d.x], t5[d.y], t5[d.z], t5[d.w]);
}

extern "C" void kernel_launch(void* const* d_in, const int* in_sizes, int n_in,
                              void* d_out, int out_size, void* d_ws, size_t ws_size,
                              hipStream_t stream) {
    const float* slabel  = (const float*)d_in[0];
    const int* parent2   = (const int*)d_in[1];
    const int* parent3   = (const int*)d_in[2];
    const int* parent4   = (const int*)d_in[3];
    const int* parent5   = (const int*)d_in[4];
    const int* idx2      = (const int*)d_in[5];
    const int* idx3      = (const int*)d_in[6];
    const int* idx4      = (const int*)d_in[7];
    const int* idx5      = (const int*)d_in[8];
    int* out = (int*)d_out;   // JAX argmax output dtype is int32

    // ---- workspace layout (dwords) ----
    // zeroed: [f3 | f4 | f5 | cnt2]
    // unzeroed: [rowid2 (N2*CAP) | tab2 | tab3 | tab4 (bytes)]
    float* f3 = (float*)d_ws;
    float* f4 = f3 + (size_t)N3 * C;
    float* f5 = f4 + (size_t)N4 * C;
    int* cnt2 = (int*)(f5 + (size_t)N5 * C);
    int* rowid2 = cnt2 + N2;                 // end of zeroed region
    unsigned char* tab2 = (unsigned char*)(rowid2 + (size_t)N2 * CAP);
    unsigned char* tab3 = tab2 + N2;
    unsigned char* tab4 = tab3 + N3;

    // zero: f3 + f4 + f5 + cnt2 = 1,028,096 dwords = 257,024 float4
    const int zero_f4 = ((N3 + N4 + N5) * C + N2) / 4;

    // 1) zero accumulators + counters (ws poisoned between calls)
    zero_kernel<<<(zero_f4 + 255) / 256, 256, 0, stream>>>((float4*)d_ws, zero_f4);

    // 2) direct-slot counting sort
    reorder_direct_kernel<<<(N1 + 255) / 256, 256, 0, stream>>>(
        parent2, cnt2, rowid2, N1);

    // 3) fused: 5-rows-per-load segment-sum + argmax->tab2 + atomic f3
    segsum_fused_kernel<<<N2 / 4, 256, 0, stream>>>(
        slabel, rowid2, cnt2, parent3, f3, tab2, N2);

    // 4) level 3: f3->f4 atomics (3072 blocks) + tab3 argmax (64 blocks)
    level_kernel<<<3072 + 64, 256, 0, stream>>>(f3, parent4, f4, tab3, N3, 3072);

    // 5) level 4: f4->f5 atomics (384 blocks) + tab4 argmax (8 blocks)
    level_kernel<<<384 + 8, 256, 0, stream>>>(f4, parent5, f5, tab4, N4, 384);

    // 6) final: tab lookups + per-block LDS tab5
    final_kernel<<<(N1 / 4 + 255) / 256, 256, 0, stream>>>(
        tab2, tab3, tab4, (const float4*)f5,
        (const int4*)idx2, (const int4*)idx3, (const int4*)idx4, (const int4*)idx5,
        (int4*)out);
}